// Round 1
// baseline (951.628 us; speedup 1.0000x reference)
//
#include <hip/hip_runtime.h>
#include <hip/hip_fp16.h>
#include <stdint.h>

#define BB 256
#define TT 511
#define VV 128
#define HH 256
#define G4 1024   // 4*H

typedef _Float16 h2_t __attribute__((ext_vector_type(2)));

__device__ __forceinline__ float fdot2(uint32_t a, uint32_t b, float c) {
  return __builtin_amdgcn_fdot2(__builtin_bit_cast(h2_t, a),
                                __builtin_bit_cast(h2_t, b), c, false);
}

__device__ __forceinline__ uint32_t pack2(float a, float b) {
  __half ha = __float2half(a), hb = __float2half(b);
  return (uint32_t)__half_as_ushort(ha) | ((uint32_t)__half_as_ushort(hb) << 16);
}

// ---------------- prep kernels ----------------

__global__ __launch_bounds__(1024) void prep_ctx_k(
    const int* __restrict__ rhythm, const int* __restrict__ meter, const int* __restrict__ keyi,
    const float* __restrict__ er, const float* __restrict__ em, const float* __restrict__ ek,
    const float* __restrict__ W, const float* __restrict__ bias, float* __restrict__ ctxW) {
  int b = blockIdx.x, j = threadIdx.x;
  int r = rhythm[b], m = meter[b], k = keyi[b];
  float acc = bias[j];
#pragma unroll
  for (int e = 0; e < 16; e++) acc += er[r*16+e] * W[(0+e)*G4 + j];
#pragma unroll
  for (int e = 0; e < 16; e++) acc += em[m*16+e] * W[(16+e)*G4 + j];
#pragma unroll
  for (int e = 0; e < 16; e++) acc += ek[k*16+e] * W[(32+e)*G4 + j];
  ctxW[b*G4 + j] = acc;
}

__global__ __launch_bounds__(1024) void prep_tune_k(
    const float* __restrict__ et, const float* __restrict__ W, float* __restrict__ tuneW) {
  int v = blockIdx.x, j = threadIdx.x;
  float acc = 0.f;
#pragma unroll
  for (int e = 0; e < 32; e++) acc += et[v*32+e] * W[(48+e)*G4 + j];
  tuneW[v*G4 + j] = acc;
}

__global__ __launch_bounds__(1024) void prep_U_k(
    const float* __restrict__ U, uint32_t* __restrict__ Up) {
  int kk = blockIdx.x, j = threadIdx.x;   // kk in [0,128): packed k-pair index
  Up[kk*G4 + j] = pack2(U[(2*kk)*G4 + j], U[(2*kk+1)*G4 + j]);
}

__global__ __launch_bounds__(128) void prep_Wd_k(
    const float* __restrict__ Wd, uint32_t* __restrict__ Wdp) {
  int kp = blockIdx.x, v = threadIdx.x;   // kp in [0,128)
  Wdp[kp*VV + v] = pack2(Wd[(2*kp)*VV + v], Wd[(2*kp+1)*VV + v]);
}

// ---------------- recurrent kernel ----------------
// one block per batch row; 512 threads; thread t owns columns t and t+512.
// U (f16-pair packed, [128][1024]) split: kk 0..95 in VGPRs, kk 96..127 in LDS.

#define NT 512
#define KREG 96
#define KLDS 32
#define RS 36   // u32 stride of an LDS-U row (32 data + 4 pad, keeps 16B align, staggers banks)
#define SMEM_BYTES (1024*RS*4 + 4096 + 512 + 2048)   // Ulds + zbuf + hpk + tune row = 154112

__global__ __launch_bounds__(NT) void lstm_rec_k(
    const int* __restrict__ tune, const int* __restrict__ tlen,
    const uint32_t* __restrict__ Up, const float* __restrict__ ctxW,
    const float* __restrict__ tuneW, __half* __restrict__ h_hist) {
  extern __shared__ uint32_t smem[];
  uint32_t* Ulds = smem;                                    // [1024][RS]
  float*    zbuf = (float*)(smem + 1024*RS);                // [1024]
  uint32_t* hpk  = (uint32_t*)(smem + 1024*RS + 1024);      // [128] packed f16 h
  int*      tlds = (int*)(smem + 1024*RS + 1024 + 128);     // [511]

  int b   = blockIdx.x;
  int tid = threadIdx.x;
  int L   = tlen[b];

  for (int i = tid; i < TT; i += NT) tlds[i] = tune[b*TT + i];
  if (tid < 128) hpk[tid] = 0u;

  uint32_t u0[KREG], u1[KREG];
#pragma unroll
  for (int kk = 0; kk < KREG; kk++) {
    u0[kk] = Up[kk*G4 + tid];
    u1[kk] = Up[kk*G4 + tid + NT];
  }
  for (int idx = tid; idx < KLDS*G4; idx += NT) {
    int kk = idx >> 10, j = idx & 1023;
    Ulds[j*RS + kk] = Up[(KREG+kk)*G4 + j];
  }
  float zc0 = ctxW[b*G4 + tid];
  float zc1 = ctxW[b*G4 + tid + NT];
  float cc  = 0.f;
  __syncthreads();

  const uint32_t* ur0 = Ulds + (size_t)tid*RS;
  const uint32_t* ur1 = Ulds + (size_t)(tid+NT)*RS;
  __half* hh_base = h_hist + (size_t)b*TT*HH;

  for (int t = 0; t < L; t++) {
    int v = tlds[t];
    float tw0 = tuneW[v*G4 + tid];
    float tw1 = tuneW[v*G4 + tid + NT];
    float a0 = 0.f, a1 = 0.f, d0 = 0.f, d1 = 0.f;
#pragma unroll
    for (int g = 0; g < KREG/4; g++) {
      uint4 h4 = *(const uint4*)(hpk + g*4);    // wave-uniform -> LDS broadcast
      a0 = fdot2(h4.x, u0[4*g+0], a0);  a1 = fdot2(h4.x, u1[4*g+0], a1);
      d0 = fdot2(h4.y, u0[4*g+1], d0);  d1 = fdot2(h4.y, u1[4*g+1], d1);
      a0 = fdot2(h4.z, u0[4*g+2], a0);  a1 = fdot2(h4.z, u1[4*g+2], a1);
      d0 = fdot2(h4.w, u0[4*g+3], d0);  d1 = fdot2(h4.w, u1[4*g+3], d1);
    }
#pragma unroll
    for (int g = 0; g < KLDS/4; g++) {
      uint4 h4 = *(const uint4*)(hpk + KREG + g*4);
      uint4 ua = *(const uint4*)(ur0 + g*4);
      uint4 ub = *(const uint4*)(ur1 + g*4);
      a0 = fdot2(h4.x, ua.x, a0);  a1 = fdot2(h4.x, ub.x, a1);
      d0 = fdot2(h4.y, ua.y, d0);  d1 = fdot2(h4.y, ub.y, d1);
      a0 = fdot2(h4.z, ua.z, a0);  a1 = fdot2(h4.z, ub.z, a1);
      d0 = fdot2(h4.w, ua.w, d0);  d1 = fdot2(h4.w, ub.w, d1);
    }
    zbuf[tid]      = zc0 + tw0 + a0 + d0;
    zbuf[tid + NT] = zc1 + tw1 + a1 + d1;
    __syncthreads();
    if (tid < HH) {
      float zi = zbuf[tid];
      float zf = zbuf[tid + 256];
      float zg = zbuf[tid + 512];
      float zo = zbuf[tid + 768];
      float gi = 1.f / (1.f + __expf(-zi));
      float gf = 1.f / (1.f + __expf(-zf));
      float e2 = __expf(2.f*zg);
      float gg = (e2 - 1.f) / (e2 + 1.f);
      float go = 1.f / (1.f + __expf(-zo));
      cc = gf*cc + gi*gg;
      float ec = __expf(2.f*cc);
      float th = (ec - 1.f) / (ec + 1.f);
      float hv = go * th;
      __half hhv = __float2half(hv);
      ((__half*)hpk)[tid] = hhv;
      hh_base[(size_t)t*HH + tid] = hhv;   // fire-and-forget history store
    }
    __syncthreads();
  }
}

// ---------------- output projection ----------------
// out[b,t,:] = h[b,t,:] @ Wd + bd  (t < L), else bd.
// h history lives (f16-packed) in d_out itself; each block stages its A-tile to
// LDS before overwriting exactly those rows -> no race (rows are block-private).

__global__ __launch_bounds__(256) void out_gemm_k(
    const uint32_t* __restrict__ hsrc, const uint32_t* __restrict__ Wdp,
    const float* __restrict__ bd, const int* __restrict__ tlen,
    float* __restrict__ out) {
  __shared__ uint32_t A[64][128];   // 32KB: 64 rows x 128 packed f16-pairs
  int bb = blockIdx.x;
  int b  = bb >> 3, t0 = (bb & 7) << 6;
  int tid = threadIdx.x;
  int L = tlen[b];
  for (int idx = tid; idx < 64*128; idx += 256) {
    int r = idx >> 7, kp = idx & 127;
    int t = t0 + r;
    A[r][kp] = (t < TT) ? hsrc[((size_t)b*TT + t)*128 + kp] : 0u;
  }
  __syncthreads();
  int v = tid & 127, rg = tid >> 7;
  float acc[32];
#pragma unroll
  for (int r = 0; r < 32; r++) acc[r] = 0.f;
  for (int kb = 0; kb < 4; kb++) {
    uint32_t w[32];
#pragma unroll
    for (int q = 0; q < 32; q++) w[q] = Wdp[(kb*32+q)*VV + v];
#pragma unroll
    for (int r = 0; r < 32; r++) {
      const uint32_t* ar = &A[rg*32 + r][kb*32];
#pragma unroll
      for (int q4 = 0; q4 < 8; q4++) {
        uint4 a4 = *(const uint4*)(ar + q4*4);   // wave-uniform -> broadcast
        acc[r] = fdot2(a4.x, w[4*q4+0], acc[r]);
        acc[r] = fdot2(a4.y, w[4*q4+1], acc[r]);
        acc[r] = fdot2(a4.z, w[4*q4+2], acc[r]);
        acc[r] = fdot2(a4.w, w[4*q4+3], acc[r]);
      }
    }
  }
  float bias = bd[v];
#pragma unroll
  for (int r = 0; r < 32; r++) {
    int t = t0 + rg*32 + r;
    if (t < TT) {
      out[((size_t)b*TT + t)*VV + v] = (t < L) ? (acc[r] + bias) : bias;
    }
  }
}

// ---------------- launch ----------------

extern "C" void kernel_launch(void* const* d_in, const int* in_sizes, int n_in,
                              void* d_out, int out_size, void* d_ws, size_t ws_size,
                              hipStream_t stream) {
  const int*   tune   = (const int*)d_in[0];
  const int*   rhythm = (const int*)d_in[1];
  const int*   meter  = (const int*)d_in[2];
  const int*   keyi   = (const int*)d_in[3];
  const int*   tlen   = (const int*)d_in[4];
  const float* er     = (const float*)d_in[5];
  const float* em     = (const float*)d_in[6];
  const float* ek     = (const float*)d_in[7];
  const float* et     = (const float*)d_in[8];
  const float* W      = (const float*)d_in[9];
  const float* U      = (const float*)d_in[10];
  const float* bias   = (const float*)d_in[11];
  const float* Wd     = (const float*)d_in[12];
  const float* bd     = (const float*)d_in[13];
  (void)in_sizes; (void)n_in; (void)out_size; (void)ws_size;

  char* ws = (char*)d_ws;
  uint32_t* Up    = (uint32_t*)(ws);                                      // 512KB
  float*    ctxW  = (float*)(ws + (512<<10));                             // 1MB
  float*    tuneW = (float*)(ws + (512<<10) + (1024<<10));                // 516KB
  uint32_t* Wdp   = (uint32_t*)(ws + (512<<10) + (1024<<10) + (516<<10)); // 64KB

  hipFuncSetAttribute((const void*)lstm_rec_k,
                      hipFuncAttributeMaxDynamicSharedMemorySize, SMEM_BYTES);

  prep_ctx_k <<<BB,    1024, 0, stream>>>(rhythm, meter, keyi, er, em, ek, W, bias, ctxW);
  prep_tune_k<<<VV+1,  1024, 0, stream>>>(et, W, tuneW);
  prep_U_k   <<<128,   1024, 0, stream>>>(U, Up);
  prep_Wd_k  <<<128,   VV,   0, stream>>>(Wd, Wdp);
  lstm_rec_k <<<BB, NT, SMEM_BYTES, stream>>>(tune, tlen, Up, ctxW, tuneW, (__half*)d_out);
  out_gemm_k <<<BB*8,  256,  0, stream>>>((const uint32_t*)d_out, Wdp, bd, tlen, (float*)d_out);
}